// Round 1
// baseline (330.614 us; speedup 1.0000x reference)
//
#include <hip/hip_runtime.h>
#include <hip/hip_bf16.h>

// SeqAttention: out = (Q K^T) V  ==  Q (K^T V)   [softmax + key_pe are dead code]
// B=8, M=2048, L=2048, H=1024. fp32 in/out; bf16 MFMA internal.
//
// R6 structure (4 launches):
//   1. transpose_kv_q: K,V fp32 [B,L,H] -> bf16 Kt,Vt [B,H,L]  (z = 0..15)
//                      + Qb = bf16(Q) [B,M,H]                  (z = 16..23, fused)
//      128(l) x 64(h) tiles: 8 float4 loads in flight/thread, 256B/row stores.
//   2. gemm1_kv:  split-L x2: W{0,1}[b][j][h] = sum_{l in half} Vt[j][l]*Kt[h][l]
//   3. qcvt_wsum: Wb = bf16(W0+W1)  (z=0; z=1 Q-fallback only if ws too small)
//   4. gemm2_qw:  O[b][m][j] = sum_h Qb[m][h]*Wb[j][h] (fp32 out)

typedef __bf16 bf16x8 __attribute__((ext_vector_type(8)));
typedef float f32x4 __attribute__((ext_vector_type(4)));
typedef unsigned short u16_t;

#define GLD_LDS16(g, l)                                                        \
  __builtin_amdgcn_global_load_lds(                                            \
      (const __attribute__((address_space(1))) void*)(g),                      \
      (__attribute__((address_space(3))) void*)(l), 16, 0, 0)

static __device__ inline u16_t f2b(float x) {
  __hip_bfloat16 h = __float2bfloat16(x);
  u16_t u;
  __builtin_memcpy(&u, &h, 2);
  return u;
}
static __device__ inline unsigned pack2(float a, float b) {
  return (unsigned)f2b(a) | ((unsigned)f2b(b) << 16);
}
static __device__ inline float b2f(u16_t u) {
  unsigned v = (unsigned)u << 16;
  float f;
  __builtin_memcpy(&f, &v, 4);
  return f;
}

// ---------------------------------------------------------------------------
// z<8: K-batch z transpose; z in 8..15: V-batch z-8; z>=16: Q convert batch z-16.
// Transpose tile: 128(l) x 64(h). Reads 128 rows x 256B; writes 64 rows x 256B.
__global__ __launch_bounds__(256) void transpose_kv_q(
    const float* __restrict__ Kin, const float* __restrict__ Vin,
    const float* __restrict__ Qin, u16_t* __restrict__ Kt,
    u16_t* __restrict__ Vt, u16_t* __restrict__ Qb, int L, int Hd, int Mq) {
  const int bz = blockIdx.z;
  const int tid = threadIdx.x;

  if (bz >= 16) {
    // --- Q fp32 -> bf16, pure streaming. 256 chunks x 8192 els per batch. ---
    const int batch = bz - 16;
    const size_t bbase = (size_t)batch * (size_t)Mq * Hd;
    const size_t chunk = (size_t)(blockIdx.y * 16 + blockIdx.x) * 8192;
    const float* src = Qin + bbase + chunk;
    u16_t* dst = Qb + bbase + chunk;
#pragma unroll
    for (int k = 0; k < 8; ++k) {
      const int idx = (k * 256 + tid) * 4;
      const float4 a = *(const float4*)(src + idx);
      unsigned o[2] = {pack2(a.x, a.y), pack2(a.z, a.w)};
      *(uint2*)(dst + idx) = *(const uint2*)o;
    }
    return;
  }

  __shared__ unsigned tile[64 * 65];  // [h][l-pair], stride 65 (65%32==1: 2-way max)
  const float* in = (bz < 8) ? Kin : Vin;
  u16_t* out = (bz < 8) ? Kt : Vt;
  const int batch = bz & 7;
  in += (size_t)batch * (size_t)L * Hd;
  out += (size_t)batch * (size_t)L * Hd;
  const int h0 = blockIdx.x * 64;
  const int l0 = blockIdx.y * 128;

  // Read phase: issue all 8 float4 loads, then pack. 2 l-rows x 4 h per thread
  // per it; 4 its cover 128 l.
  const int h4 = (tid & 15) * 4;
  const int lp0 = tid >> 4;  // l-pair 0..15 (+16*it)
  float4 r0[4], r1[4];
#pragma unroll
  for (int it = 0; it < 4; ++it) {
    const int l = 2 * (lp0 + 16 * it);
    r0[it] = *(const float4*)(in + (size_t)(l0 + l) * Hd + h0 + h4);
    r1[it] = *(const float4*)(in + (size_t)(l0 + l + 1) * Hd + h0 + h4);
  }
#pragma unroll
  for (int it = 0; it < 4; ++it) {
    const int lp = lp0 + 16 * it;
    tile[(h4 + 0) * 65 + lp] = pack2(r0[it].x, r1[it].x);
    tile[(h4 + 1) * 65 + lp] = pack2(r0[it].y, r1[it].y);
    tile[(h4 + 2) * 65 + lp] = pack2(r0[it].z, r1[it].z);
    tile[(h4 + 3) * 65 + lp] = pack2(r0[it].w, r1[it].w);
  }
  __syncthreads();

  // Write phase: 4 threads per h-row, 64B each -> 256B contiguous per row.
  const int h = tid >> 2;
  const int q = tid & 3;
  unsigned u[16];
#pragma unroll
  for (int j = 0; j < 16; ++j) u[j] = tile[h * 65 + 16 * q + j];
  u16_t* dst = out + (size_t)(h0 + h) * L + l0 + 32 * q;
  *(uint4*)(dst + 0)  = *(const uint4*)(u + 0);
  *(uint4*)(dst + 8)  = *(const uint4*)(u + 4);
  *(uint4*)(dst + 16) = *(const uint4*)(u + 8);
  *(uint4*)(dst + 24) = *(const uint4*)(u + 12);
}

// ---------------------------------------------------------------------------
static __device__ inline void store_c(float* p, float v) { *p = v; }
static __device__ inline void store_c(u16_t* p, float v) { *p = f2b(v); }

// C[m][n] = sum_{k in split kh} A[m][k]*Bt[n][k].  (R3-verified core)
// blockIdx.x = ((kh*Tiles + t) << 3) | batch;  Tiles = 1<<tile_shift;
// t -> (tm = t>>3, tn = t&7); N must be 1024. K = per-split extent, ld = row stride.
// LDS: As[row][slot*8..], slot = chunk ^ (row&7)  (BK=64, 8 chunks/row).
template <typename OutT>
static __device__ inline void gemm_bt_body(
    const u16_t* __restrict__ A, const u16_t* __restrict__ Bt,
    OutT* __restrict__ C, int N, int K, int ldA, int ldB,
    long sA, long sB, long sC, int tile_shift, long sCsplit) {
  __shared__ __align__(16) u16_t As[128 * 64];
  __shared__ __align__(16) u16_t Bs[128 * 64];

  const int batch = blockIdx.x & 7;
  const unsigned u = blockIdx.x >> 3;
  const int kh = (int)(u >> tile_shift);
  const unsigned t = u & ((1u << tile_shift) - 1u);
  const int m0 = (int)(t >> 3) * 128;
  const int n0 = (int)(t & 7) * 128;

  A  += (size_t)batch * (size_t)sA + (size_t)kh * (size_t)K;
  Bt += (size_t)batch * (size_t)sB + (size_t)kh * (size_t)K;
  C  += (size_t)batch * (size_t)sC + (size_t)kh * (size_t)sCsplit;

  const int tid = threadIdx.x;
  const int lane = tid & 63;
  const int w  = tid >> 6;
  const int wm = w & 1;
  const int wn = w >> 1;
  const int s  = lane & 15;
  const int q  = lane >> 4;

  const u16_t* gA[4];
  const u16_t* gB[4];
  u16_t* lA[4];
  u16_t* lB[4];
#pragma unroll
  for (int j = 0; j < 4; ++j) {
    const int i = tid + 256 * j;
    const int row = i >> 3;
    const int gchunk = (i & 7) ^ (row & 7);
    gA[j] = A  + (size_t)(m0 + row) * ldA + gchunk * 8;
    gB[j] = Bt + (size_t)(n0 + row) * ldB + gchunk * 8;
    lA[j] = As + i * 8;
    lB[j] = Bs + i * 8;
  }

  f32x4 acc[4][4];
#pragma unroll
  for (int r = 0; r < 4; ++r)
#pragma unroll
    for (int c = 0; c < 4; ++c) acc[r][c] = (f32x4){0.f, 0.f, 0.f, 0.f};

  const int s7 = s & 7;

  for (int k0 = 0; k0 < K; k0 += 64) {
#pragma unroll
    for (int j = 0; j < 4; ++j) {
      GLD_LDS16(gA[j] + k0, lA[j]);
      GLD_LDS16(gB[j] + k0, lB[j]);
    }
    __syncthreads();

#pragma unroll
    for (int kk = 0; kk < 2; ++kk) {
      const int slot = (kk * 4 + q) ^ s7;
      bf16x8 af[4], bfr[4];
#pragma unroll
      for (int r = 0; r < 4; ++r)
        af[r] = *(const bf16x8*)(As + (64 * wm + 16 * r + s) * 64 + slot * 8);
#pragma unroll
      for (int c = 0; c < 4; ++c)
        bfr[c] = *(const bf16x8*)(Bs + (64 * wn + 16 * c + s) * 64 + slot * 8);
#pragma unroll
      for (int r = 0; r < 4; ++r)
#pragma unroll
        for (int c = 0; c < 4; ++c)
          acc[r][c] = __builtin_amdgcn_mfma_f32_16x16x32_bf16(af[r], bfr[c],
                                                              acc[r][c], 0, 0, 0);
    }
    __syncthreads();
  }

  // C/D layout (m89-verified): col = lane&15, row = (lane>>4)*4 + reg
#pragma unroll
  for (int r = 0; r < 4; ++r) {
#pragma unroll
    for (int c = 0; c < 4; ++c) {
      const int col = n0 + 64 * wn + 16 * c + s;
#pragma unroll
      for (int e = 0; e < 4; ++e) {
        const int row = m0 + 64 * wm + 16 * r + q * 4 + e;
        store_c(&C[(size_t)row * N + col], acc[r][c][e]);
      }
    }
  }
}

// GEMM1: W-halves from Vt,Kt. grid.x = B * 64 * 2 (tile_shift=6, kh in {0,1}).
__global__ __launch_bounds__(256) void gemm1_kv(
    const u16_t* __restrict__ Vt, const u16_t* __restrict__ Kt,
    u16_t* __restrict__ W0, int N, int K, int ld, long sA, long sB, long sC,
    long sCsplit) {
  gemm_bt_body<u16_t>(Vt, Kt, W0, N, K, ld, ld, sA, sB, sC, 6, sCsplit);
}

// GEMM2: O from Qb,Wb. grid.x = B * 128 (tile_shift=7, kh=0).
__global__ __launch_bounds__(256) void gemm2_qw(
    const u16_t* __restrict__ Qb, const u16_t* __restrict__ Wb,
    float* __restrict__ C, int N, int K, long sA, long sB, long sC) {
  gemm_bt_body<float>(Qb, Wb, C, N, K, K, K, sA, sB, sC, 7, 0);
}

// ---------------------------------------------------------------------------
// z=0: Wb = bf16(W0+W1), 512 blocks/batch x 2048 els.
// z=1: Qb = bf16(Q) fallback (only launched when ws lacks room for separate Qb).
__global__ __launch_bounds__(256) void qcvt_wsum(
    const float* __restrict__ Q, const u16_t* __restrict__ W0,
    const u16_t* __restrict__ W1, u16_t* __restrict__ Qb,
    u16_t* __restrict__ Wb, size_t nQbatch, size_t nWbatch) {
  const int batch = blockIdx.y;
  if (blockIdx.z == 0) {
    const size_t base = (size_t)batch * nWbatch +
                        (size_t)blockIdx.x * 2048 + threadIdx.x * 8;
    const uint4 u0 = *(const uint4*)(W0 + base);
    const uint4 u1 = *(const uint4*)(W1 + base);
    const u16_t* p0 = (const u16_t*)&u0;
    const u16_t* p1 = (const u16_t*)&u1;
    u16_t o[8];
#pragma unroll
    for (int j = 0; j < 8; ++j) o[j] = f2b(b2f(p0[j]) + b2f(p1[j]));
    *(uint4*)(Wb + base) = *(const uint4*)o;
  } else {
    const size_t base = (size_t)batch * nQbatch +
                        (size_t)blockIdx.x * 4096 + threadIdx.x * 16;
    const float* src = Q + base;
    u16_t* dst = Qb + base;
#pragma unroll
    for (int half = 0; half < 2; ++half) {
      const float4 a = *(const float4*)(src + half * 8);
      const float4 b = *(const float4*)(src + half * 8 + 4);
      unsigned o[4] = {pack2(a.x, a.y), pack2(a.z, a.w),
                       pack2(b.x, b.y), pack2(b.z, b.w)};
      *(uint4*)(dst + half * 8) = *(const uint4*)o;
    }
  }
}

// ---------------------------------------------------------------------------
extern "C" void kernel_launch(void* const* d_in, const int* in_sizes, int n_in,
                              void* d_out, int out_size, void* d_ws, size_t ws_size,
                              hipStream_t stream) {
  const int B = 8, M = 2048, L = 2048, H = 1024;

  const float* q = (const float*)d_in[0];  // [B,M,H] fp32
  const float* k = (const float*)d_in[1];  // [B,L,H] fp32
  const float* v = (const float*)d_in[2];  // [B,L,H] fp32

  const size_t nKt = (size_t)B * H * L;  // 16.78M els
  const size_t nW  = (size_t)B * H * H;  // 8.39M els
  const size_t nQ  = (size_t)B * M * H;  // 16.78M els
  const size_t need_base  = (2 * nKt + 2 * nW) * sizeof(u16_t);       // 100.7 MB
  const size_t need_fused = need_base + nQ * sizeof(u16_t);           // 134.2 MB
  if (ws_size < need_base) return;
  const bool fused_q = ws_size >= need_fused;

  u16_t* Kt = (u16_t*)d_ws;  // [B,H,L]
  u16_t* Vt = Kt + nKt;      // [B,H,L]; reused as Wb after gemm1
  u16_t* W0 = Vt + nKt;      // [B,H,H] half-L partial 0
  u16_t* W1 = W0 + nW;       // [B,H,H] half-L partial 1
  u16_t* Qsep = W1 + nW;     // [B,M,H] (fused path only)
  u16_t* Qb = fused_q ? Qsep : Kt;  // fallback: alias Kt (written after gemm1)
  u16_t* Wb = Vt;

  dim3 tb(256);

  // 1. K,V transpose+convert (+ Q convert when fused).
  transpose_kv_q<<<dim3(H / 64, L / 128, fused_q ? 24 : 16), tb, 0, stream>>>(
      k, v, q, Kt, Vt, Qb, L, H, M);

  // 2. GEMM1 split-L x2: W{0,1}[j][h] = sum_{half} Vt[j][l]*Kt[h][l]
  gemm1_kv<<<dim3(B * 64 * 2), tb, 0, stream>>>(
      Vt, Kt, W0, H, L / 2, L, (long)H * L, (long)H * L, (long)H * H,
      (long)B * H * H);

  // 3. Wb = bf16(W0+W1)  (+ Qb = bf16(Q) only in fallback path).
  qcvt_wsum<<<dim3(512, B, fused_q ? 1 : 2), tb, 0, stream>>>(
      q, W0, W1, Qb, Wb, (size_t)M * H, (size_t)H * H);

  // 4. GEMM2: O[m][j] = sum_h Qb[m][h]*Wb[j][h]
  gemm2_qw<<<dim3(B * 128), tb, 0, stream>>>(
      Qb, Wb, (float*)d_out, H, H, (long)M * H, (long)H * H, (long)M * H);
}

// Round 2
// 330.391 us; speedup vs baseline: 1.0007x; 1.0007x over previous
//
#include <hip/hip_runtime.h>
#include <hip/hip_bf16.h>

// SeqAttention: out = (Q K^T) V  ==  Q (K^T V)   [softmax + key_pe are dead code]
// B=8, M=2048, L=2048, H=1024. fp32 in/out; bf16 MFMA internal.
//
// R7 structure (4 launches):
//   1. transpose_kv: K,V fp32 [B,L,H] -> bf16 Kt,Vt [B,H,ldT] (rows PADDED to
//      ldT=L+16 to break 4KB channel camping). 512(l)x64(h) tiles: write phase
//      is one full row-chunk per store instr (1KB contiguous per wave-instr).
//   2. gemm1_kv:  split-L x2: W{0,1}[b][j][h] = sum_{l in half} Vt[j][l]*Kt[h][l]
//   3. qcvt_wsum: z=0: Wb = bf16(W0+W1); z=1: Qb = bf16(Q)  (streaming, ~6 TB/s)
//   4. gemm2_qw:  O[b][m][j] = sum_h Qb[m][h]*Wb[j][h] (fp32 out)

typedef __bf16 bf16x8 __attribute__((ext_vector_type(8)));
typedef float f32x4 __attribute__((ext_vector_type(4)));
typedef unsigned short u16_t;

#define GLD_LDS16(g, l)                                                        \
  __builtin_amdgcn_global_load_lds(                                            \
      (const __attribute__((address_space(1))) void*)(g),                      \
      (__attribute__((address_space(3))) void*)(l), 16, 0, 0)

static __device__ inline u16_t f2b(float x) {
  __hip_bfloat16 h = __float2bfloat16(x);
  u16_t u;
  __builtin_memcpy(&u, &h, 2);
  return u;
}
static __device__ inline unsigned pack2(float a, float b) {
  return (unsigned)f2b(a) | ((unsigned)f2b(b) << 16);
}
static __device__ inline float b2f(u16_t u) {
  unsigned v = (unsigned)u << 16;
  float f;
  __builtin_memcpy(&f, &v, 4);
  return f;
}

// ---------------------------------------------------------------------------
// z<8: K-batch z; z>=8: V-batch z-8. fp32 [L,H] -> bf16 [H, ldT] (row-padded).
// Tile 512(l) x 64(h). Read: 8 float4 in flight per group. Write: one output
// row (1KB) per wave store-instruction, fully contiguous.
__global__ __launch_bounds__(256) void transpose_kv(
    const float* __restrict__ Kin, const float* __restrict__ Vin,
    u16_t* __restrict__ Kt, u16_t* __restrict__ Vt, int L, int Hd, int ldT) {
  __shared__ unsigned tile[64][260];  // [h][l-pair]; 260%32==4, 65KB
  const int bz = blockIdx.z;
  const float* in = (bz < 8) ? Kin : Vin;
  u16_t* out = (bz < 8) ? Kt : Vt;
  const int batch = bz & 7;
  in += (size_t)batch * (size_t)L * Hd;
  out += (size_t)batch * (size_t)Hd * ldT;
  const int h0 = blockIdx.x * 64;
  const int l0 = blockIdx.y * 512;

  const int tid = threadIdx.x;
  const int h4 = (tid & 15) * 4;  // 4 h-values per thread
  const int lp0 = tid >> 4;       // l-pair 0..15 (+16*it)

#pragma unroll
  for (int g = 0; g < 4; ++g) {
    float4 r0[4], r1[4];
#pragma unroll
    for (int it = 0; it < 4; ++it) {
      const int lp = lp0 + 16 * (4 * g + it);
      const int l = l0 + 2 * lp;
      r0[it] = *(const float4*)(in + (size_t)l * Hd + h0 + h4);
      r1[it] = *(const float4*)(in + (size_t)(l + 1) * Hd + h0 + h4);
    }
#pragma unroll
    for (int it = 0; it < 4; ++it) {
      const int lp = lp0 + 16 * (4 * g + it);
      tile[h4 + 0][lp] = pack2(r0[it].x, r1[it].x);
      tile[h4 + 1][lp] = pack2(r0[it].y, r1[it].y);
      tile[h4 + 2][lp] = pack2(r0[it].z, r1[it].z);
      tile[h4 + 3][lp] = pack2(r0[it].w, r1[it].w);
    }
  }
  __syncthreads();

  // Write phase: wave w owns rows h = 16w..16w+15; all 64 lanes on ONE row per
  // store -> each uint4 store instr is 1KB contiguous in the output.
  const int wv = tid >> 6;
  const int lane = tid & 63;
#pragma unroll
  for (int r = 0; r < 16; ++r) {
    const int h = wv * 16 + r;
    unsigned u[4];
#pragma unroll
    for (int j = 0; j < 4; ++j) u[j] = tile[h][4 * lane + j];
    *(uint4*)(out + (size_t)(h0 + h) * ldT + l0 + lane * 8) = *(const uint4*)u;
  }
}

// ---------------------------------------------------------------------------
static __device__ inline void store_c(float* p, float v) { *p = v; }
static __device__ inline void store_c(u16_t* p, float v) { *p = f2b(v); }

// C[m][n] = sum_{k in split kh} A[m][k]*Bt[n][k].  (R3-verified core)
// blockIdx.x = ((kh*Tiles + t) << 3) | batch;  Tiles = 1<<tile_shift;
// t -> (tm = t>>3, tn = t&7); N must be 1024. K = per-split extent, ld = row stride.
// LDS: As[row][slot*8..], slot = chunk ^ (row&7)  (BK=64, 8 chunks/row).
template <typename OutT>
static __device__ inline void gemm_bt_body(
    const u16_t* __restrict__ A, const u16_t* __restrict__ Bt,
    OutT* __restrict__ C, int N, int K, int ldA, int ldB,
    long sA, long sB, long sC, int tile_shift, long sCsplit) {
  __shared__ __align__(16) u16_t As[128 * 64];
  __shared__ __align__(16) u16_t Bs[128 * 64];

  const int batch = blockIdx.x & 7;
  const unsigned u = blockIdx.x >> 3;
  const int kh = (int)(u >> tile_shift);
  const unsigned t = u & ((1u << tile_shift) - 1u);
  const int m0 = (int)(t >> 3) * 128;
  const int n0 = (int)(t & 7) * 128;

  A  += (size_t)batch * (size_t)sA + (size_t)kh * (size_t)K;
  Bt += (size_t)batch * (size_t)sB + (size_t)kh * (size_t)K;
  C  += (size_t)batch * (size_t)sC + (size_t)kh * (size_t)sCsplit;

  const int tid = threadIdx.x;
  const int lane = tid & 63;
  const int w  = tid >> 6;
  const int wm = w & 1;
  const int wn = w >> 1;
  const int s  = lane & 15;
  const int q  = lane >> 4;

  const u16_t* gA[4];
  const u16_t* gB[4];
  u16_t* lA[4];
  u16_t* lB[4];
#pragma unroll
  for (int j = 0; j < 4; ++j) {
    const int i = tid + 256 * j;
    const int row = i >> 3;
    const int gchunk = (i & 7) ^ (row & 7);
    gA[j] = A  + (size_t)(m0 + row) * ldA + gchunk * 8;
    gB[j] = Bt + (size_t)(n0 + row) * ldB + gchunk * 8;
    lA[j] = As + i * 8;
    lB[j] = Bs + i * 8;
  }

  f32x4 acc[4][4];
#pragma unroll
  for (int r = 0; r < 4; ++r)
#pragma unroll
    for (int c = 0; c < 4; ++c) acc[r][c] = (f32x4){0.f, 0.f, 0.f, 0.f};

  const int s7 = s & 7;

  for (int k0 = 0; k0 < K; k0 += 64) {
#pragma unroll
    for (int j = 0; j < 4; ++j) {
      GLD_LDS16(gA[j] + k0, lA[j]);
      GLD_LDS16(gB[j] + k0, lB[j]);
    }
    __syncthreads();

#pragma unroll
    for (int kk = 0; kk < 2; ++kk) {
      const int slot = (kk * 4 + q) ^ s7;
      bf16x8 af[4], bfr[4];
#pragma unroll
      for (int r = 0; r < 4; ++r)
        af[r] = *(const bf16x8*)(As + (64 * wm + 16 * r + s) * 64 + slot * 8);
#pragma unroll
      for (int c = 0; c < 4; ++c)
        bfr[c] = *(const bf16x8*)(Bs + (64 * wn + 16 * c + s) * 64 + slot * 8);
#pragma unroll
      for (int r = 0; r < 4; ++r)
#pragma unroll
        for (int c = 0; c < 4; ++c)
          acc[r][c] = __builtin_amdgcn_mfma_f32_16x16x32_bf16(af[r], bfr[c],
                                                              acc[r][c], 0, 0, 0);
    }
    __syncthreads();
  }

  // C/D layout (m89-verified): col = lane&15, row = (lane>>4)*4 + reg
#pragma unroll
  for (int r = 0; r < 4; ++r) {
#pragma unroll
    for (int c = 0; c < 4; ++c) {
      const int col = n0 + 64 * wn + 16 * c + s;
#pragma unroll
      for (int e = 0; e < 4; ++e) {
        const int row = m0 + 64 * wm + 16 * r + q * 4 + e;
        store_c(&C[(size_t)row * N + col], acc[r][c][e]);
      }
    }
  }
}

// GEMM1: W-halves from Vt,Kt. grid.x = B * 64 * 2 (tile_shift=6, kh in {0,1}).
__global__ __launch_bounds__(256) void gemm1_kv(
    const u16_t* __restrict__ Vt, const u16_t* __restrict__ Kt,
    u16_t* __restrict__ W0, int N, int K, int ld, long sA, long sB, long sC,
    long sCsplit) {
  gemm_bt_body<u16_t>(Vt, Kt, W0, N, K, ld, ld, sA, sB, sC, 6, sCsplit);
}

// GEMM2: O from Qb,Wb. grid.x = B * 128 (tile_shift=7, kh=0).
__global__ __launch_bounds__(256) void gemm2_qw(
    const u16_t* __restrict__ Qb, const u16_t* __restrict__ Wb,
    float* __restrict__ C, int N, int K, long sA, long sB, long sC) {
  gemm_bt_body<float>(Qb, Wb, C, N, K, K, K, sA, sB, sC, 7, 0);
}

// ---------------------------------------------------------------------------
// z=0: Wb = bf16(W0+W1), 512 blocks/batch x 2048 els.
// z=1: Qb = bf16(Q),      512 blocks/batch x 4096 els.  (streaming path)
__global__ __launch_bounds__(256) void qcvt_wsum(
    const float* __restrict__ Q, const u16_t* __restrict__ W0,
    const u16_t* __restrict__ W1, u16_t* __restrict__ Qb,
    u16_t* __restrict__ Wb, size_t nQbatch, size_t nWbatch) {
  const int batch = blockIdx.y;
  if (blockIdx.z == 0) {
    const size_t base = (size_t)batch * nWbatch +
                        (size_t)blockIdx.x * 2048 + threadIdx.x * 8;
    const uint4 u0 = *(const uint4*)(W0 + base);
    const uint4 u1 = *(const uint4*)(W1 + base);
    const u16_t* p0 = (const u16_t*)&u0;
    const u16_t* p1 = (const u16_t*)&u1;
    u16_t o[8];
#pragma unroll
    for (int j = 0; j < 8; ++j) o[j] = f2b(b2f(p0[j]) + b2f(p1[j]));
    *(uint4*)(Wb + base) = *(const uint4*)o;
  } else {
    const size_t base = (size_t)batch * nQbatch +
                        (size_t)blockIdx.x * 4096 + threadIdx.x * 16;
    const float* src = Q + base;
    u16_t* dst = Qb + base;
#pragma unroll
    for (int half = 0; half < 2; ++half) {
      const float4 a = *(const float4*)(src + half * 8);
      const float4 b = *(const float4*)(src + half * 8 + 4);
      unsigned o[4] = {pack2(a.x, a.y), pack2(a.z, a.w),
                       pack2(b.x, b.y), pack2(b.z, b.w)};
      *(uint4*)(dst + half * 8) = *(const uint4*)o;
    }
  }
}

// ---------------------------------------------------------------------------
extern "C" void kernel_launch(void* const* d_in, const int* in_sizes, int n_in,
                              void* d_out, int out_size, void* d_ws, size_t ws_size,
                              hipStream_t stream) {
  const int B = 8, M = 2048, L = 2048, H = 1024;
  const int ldT = L + 16;  // padded Kt/Vt row stride (4128B) breaks 4KB camping

  const float* q = (const float*)d_in[0];  // [B,M,H] fp32
  const float* k = (const float*)d_in[1];  // [B,L,H] fp32
  const float* v = (const float*)d_in[2];  // [B,L,H] fp32

  const size_t nKtP = (size_t)B * H * ldT;  // 16.91M els (padded)
  const size_t nW   = (size_t)B * H * H;    // 8.39M els
  const size_t nQ   = (size_t)B * M * H;    // 16.78M els  (<= nKtP: alias ok)
  const size_t need = (2 * nKtP + 2 * nW) * sizeof(u16_t);  // 101.2 MB
  if (ws_size < need) return;

  u16_t* Kt = (u16_t*)d_ws;   // [B,H,ldT]; reused as Qb [B,M,H] after gemm1
  u16_t* Vt = Kt + nKtP;      // [B,H,ldT]; reused as Wb [B,H,H] after gemm1
  u16_t* W0 = Vt + nKtP;      // [B,H,H] half-L partial 0
  u16_t* W1 = W0 + nW;        // [B,H,H] half-L partial 1
  u16_t* Qb = Kt;
  u16_t* Wb = Vt;
  (void)nQ;

  dim3 tb(256);

  // 1. K,V transpose+convert into padded [B,H,ldT].
  transpose_kv<<<dim3(H / 64, L / 512, 16), tb, 0, stream>>>(k, v, Kt, Vt, L, H,
                                                             ldT);

  // 2. GEMM1 split-L x2: W{0,1}[j][h] = sum_{half} Vt[j][l]*Kt[h][l]
  gemm1_kv<<<dim3(B * 64 * 2), tb, 0, stream>>>(
      Vt, Kt, W0, H, L / 2, ldT, (long)H * ldT, (long)H * ldT, (long)H * H,
      (long)B * H * H);

  // 3. Wb = bf16(W0+W1); Qb = bf16(Q).
  qcvt_wsum<<<dim3(512, B, 2), tb, 0, stream>>>(
      q, W0, W1, Qb, Wb, (size_t)M * H, (size_t)H * H);

  // 4. GEMM2: O[m][j] = sum_h Qb[m][h]*Wb[j][h]
  gemm2_qw<<<dim3(B * 128), tb, 0, stream>>>(
      Qb, Wb, (float*)d_out, H, H, (long)M * H, (long)H * H, (long)M * H);
}

// Round 3
// 308.914 us; speedup vs baseline: 1.0702x; 1.0695x over previous
//
#include <hip/hip_runtime.h>
#include <hip/hip_bf16.h>

// SeqAttention: out = (Q K^T) V  ==  Q (K^T V)   [softmax + key_pe are dead code]
// B=8, M=2048, L=2048, H=1024. fp32 in/out; bf16 MFMA internal.
//
// R8 structure (4 launches):
//   1. transpose_kv: K,V fp32 [B,L,H] -> bf16 Kt,Vt [B,H,ldT] (ldT=L+16).
//   2. gemm1_kv:  split-L x2: W{0,1}[b][j][h] = sum_{l in half} Vt[j][l]*Kt[h][l]
//                 NEW: 256^2 x BK64 tile, 512 thr / 8 waves, double-buffered LDS
//                 (128KB), prefetch-before-compute, 1 barrier per K-step.
//   3. qcvt_wsum: z=0: Wb = bf16(W0+W1); z=1: Qb = bf16(Q)
//   4. gemm2_qw:  O[b][m][j] = sum_h Qb[m][h]*Wb[j][h] (fp32 out), same 256^2 body

typedef __bf16 bf16x8 __attribute__((ext_vector_type(8)));
typedef float f32x4 __attribute__((ext_vector_type(4)));
typedef unsigned short u16_t;

#define GLD_LDS16(g, l)                                                        \
  __builtin_amdgcn_global_load_lds(                                            \
      (const __attribute__((address_space(1))) void*)(g),                      \
      (__attribute__((address_space(3))) void*)(l), 16, 0, 0)

static __device__ inline u16_t f2b(float x) {
  __hip_bfloat16 h = __float2bfloat16(x);
  u16_t u;
  __builtin_memcpy(&u, &h, 2);
  return u;
}
static __device__ inline unsigned pack2(float a, float b) {
  return (unsigned)f2b(a) | ((unsigned)f2b(b) << 16);
}
static __device__ inline float b2f(u16_t u) {
  unsigned v = (unsigned)u << 16;
  float f;
  __builtin_memcpy(&f, &v, 4);
  return f;
}

// ---------------------------------------------------------------------------
// z<8: K-batch z; z>=8: V-batch z-8. fp32 [L,H] -> bf16 [H, ldT] (row-padded).
__global__ __launch_bounds__(256) void transpose_kv(
    const float* __restrict__ Kin, const float* __restrict__ Vin,
    u16_t* __restrict__ Kt, u16_t* __restrict__ Vt, int L, int Hd, int ldT) {
  __shared__ unsigned tile[64][260];
  const int bz = blockIdx.z;
  const float* in = (bz < 8) ? Kin : Vin;
  u16_t* out = (bz < 8) ? Kt : Vt;
  const int batch = bz & 7;
  in += (size_t)batch * (size_t)L * Hd;
  out += (size_t)batch * (size_t)Hd * ldT;
  const int h0 = blockIdx.x * 64;
  const int l0 = blockIdx.y * 512;

  const int tid = threadIdx.x;
  const int h4 = (tid & 15) * 4;
  const int lp0 = tid >> 4;

#pragma unroll
  for (int g = 0; g < 4; ++g) {
    float4 r0[4], r1[4];
#pragma unroll
    for (int it = 0; it < 4; ++it) {
      const int lp = lp0 + 16 * (4 * g + it);
      const int l = l0 + 2 * lp;
      r0[it] = *(const float4*)(in + (size_t)l * Hd + h0 + h4);
      r1[it] = *(const float4*)(in + (size_t)(l + 1) * Hd + h0 + h4);
    }
#pragma unroll
    for (int it = 0; it < 4; ++it) {
      const int lp = lp0 + 16 * (4 * g + it);
      tile[h4 + 0][lp] = pack2(r0[it].x, r1[it].x);
      tile[h4 + 1][lp] = pack2(r0[it].y, r1[it].y);
      tile[h4 + 2][lp] = pack2(r0[it].z, r1[it].z);
      tile[h4 + 3][lp] = pack2(r0[it].w, r1[it].w);
    }
  }
  __syncthreads();

  const int wv = tid >> 6;
  const int lane = tid & 63;
#pragma unroll
  for (int r = 0; r < 16; ++r) {
    const int h = wv * 16 + r;
    unsigned u[4];
#pragma unroll
    for (int j = 0; j < 4; ++j) u[j] = tile[h][4 * lane + j];
    *(uint4*)(out + (size_t)(h0 + h) * ldT + l0 + lane * 8) = *(const uint4*)u;
  }
}

// ---------------------------------------------------------------------------
static __device__ inline void store_c(float* p, float v) { *p = v; }
static __device__ inline void store_c(u16_t* p, float v) { *p = f2b(v); }

// 256^2 x BK64 GEMM body, 512 threads (8 waves = 2m x 4n), per-wave 128x64.
// C[m][n] = sum_{k in split kh} A[m][k]*Bt[n][k].
// blockIdx.x = ((kh*Tiles + t) << 3) | batch;  Tiles = 1<<tile_shift;
// t -> (tm = t>>2, tn = t&3); N must be 1024 (4 n-tiles). K even multiple of 128.
// LDS: double-buffered; As[row][slot*8..], slot = chunk ^ (row&7)  (R3-verified
// both-sides swizzle, carried over unchanged).
template <typename OutT>
static __device__ inline void gemm256_body(
    const u16_t* __restrict__ A, const u16_t* __restrict__ Bt,
    OutT* __restrict__ C, int N, int K, int ldA, int ldB,
    long sA, long sB, long sC, int tile_shift, long sCsplit) {
  __shared__ __align__(16) u16_t As[2][256 * 64];
  __shared__ __align__(16) u16_t Bs[2][256 * 64];

  const int batch = blockIdx.x & 7;
  const unsigned u = blockIdx.x >> 3;
  const int kh = (int)(u >> tile_shift);
  const unsigned t = u & ((1u << tile_shift) - 1u);
  const int m0 = (int)(t >> 2) * 256;
  const int n0 = (int)(t & 3) * 256;

  A  += (size_t)batch * (size_t)sA + (size_t)kh * (size_t)K;
  Bt += (size_t)batch * (size_t)sB + (size_t)kh * (size_t)K;
  C  += (size_t)batch * (size_t)sC + (size_t)kh * (size_t)sCsplit;

  const int tid = threadIdx.x;
  const int lane = tid & 63;
  const int w  = tid >> 6;  // 0..7
  const int wm = w & 1;
  const int wn = w >> 1;    // 0..3
  const int s  = lane & 15;
  const int q  = lane >> 4;
  const int s7 = s & 7;

  // Staging addresses: i = tid + 512*j covers 2048 slots (256 rows x 8 chunks).
  const u16_t* gA[4];
  const u16_t* gB[4];
  int lofs[4];
#pragma unroll
  for (int j = 0; j < 4; ++j) {
    const int i = tid + 512 * j;
    const int row = i >> 3;                    // 0..255
    const int gchunk = (i & 7) ^ (row & 7);    // pre-swizzled global source
    gA[j] = A  + (size_t)(m0 + row) * ldA + gchunk * 8;
    gB[j] = Bt + (size_t)(n0 + row) * ldB + gchunk * 8;
    lofs[j] = i * 8;                           // linear LDS dest (rule #21)
  }

  f32x4 acc[8][4];
#pragma unroll
  for (int r = 0; r < 8; ++r)
#pragma unroll
    for (int c = 0; c < 4; ++c) acc[r][c] = (f32x4){0.f, 0.f, 0.f, 0.f};

  auto STAGE = [&](u16_t* dA, u16_t* dB, int k0) {
#pragma unroll
    for (int j = 0; j < 4; ++j) GLD_LDS16(gA[j] + k0, dA + lofs[j]);
#pragma unroll
    for (int j = 0; j < 4; ++j) GLD_LDS16(gB[j] + k0, dB + lofs[j]);
  };

  auto COMPUTE = [&](const u16_t* As_, const u16_t* Bs_) {
#pragma unroll
    for (int kk = 0; kk < 2; ++kk) {
      const int slot = (kk * 4 + q) ^ s7;
      bf16x8 bfr[4];
#pragma unroll
      for (int c = 0; c < 4; ++c)
        bfr[c] = *(const bf16x8*)(Bs_ + (64 * wn + 16 * c + s) * 64 + slot * 8);
#pragma unroll
      for (int r = 0; r < 8; ++r) {
        const bf16x8 af =
            *(const bf16x8*)(As_ + (128 * wm + 16 * r + s) * 64 + slot * 8);
#pragma unroll
        for (int c = 0; c < 4; ++c)
          acc[r][c] = __builtin_amdgcn_mfma_f32_16x16x32_bf16(af, bfr[c],
                                                              acc[r][c], 0, 0, 0);
      }
    }
  };

  const int nt = K / 64;  // 16 for both gemms (even)
  STAGE(As[0], Bs[0], 0);
  __syncthreads();
  for (int tt = 0; tt < nt; tt += 2) {
    if (tt + 1 < nt) STAGE(As[1], Bs[1], (tt + 1) * 64);  // prefetch flies under MFMA
    COMPUTE(As[0], Bs[0]);
    __syncthreads();  // drains prefetch + releases buf0 for next stage
    if (tt + 2 < nt) STAGE(As[0], Bs[0], (tt + 2) * 64);
    COMPUTE(As[1], Bs[1]);
    __syncthreads();
  }

  // C/D layout (m89-verified): col = lane&15, row = (lane>>4)*4 + reg
#pragma unroll
  for (int r = 0; r < 8; ++r) {
#pragma unroll
    for (int c = 0; c < 4; ++c) {
      const int col = n0 + 64 * wn + 16 * c + s;
#pragma unroll
      for (int e = 0; e < 4; ++e) {
        const int row = m0 + 128 * wm + 16 * r + q * 4 + e;
        store_c(&C[(size_t)row * N + col], acc[r][c][e]);
      }
    }
  }
}

// GEMM1: W-halves from Vt,Kt. grid.x = B * 16 * 2 (tile_shift=4, kh in {0,1}).
__global__ __launch_bounds__(512) void gemm1_kv(
    const u16_t* __restrict__ Vt, const u16_t* __restrict__ Kt,
    u16_t* __restrict__ W0, int N, int K, int ld, long sA, long sB, long sC,
    long sCsplit) {
  gemm256_body<u16_t>(Vt, Kt, W0, N, K, ld, ld, sA, sB, sC, 4, sCsplit);
}

// GEMM2: O from Qb,Wb. grid.x = B * 32 (tile_shift=5, kh=0).
__global__ __launch_bounds__(512) void gemm2_qw(
    const u16_t* __restrict__ Qb, const u16_t* __restrict__ Wb,
    float* __restrict__ C, int N, int K, long sA, long sB, long sC) {
  gemm256_body<float>(Qb, Wb, C, N, K, K, K, sA, sB, sC, 5, 0);
}

// ---------------------------------------------------------------------------
// z=0: Wb = bf16(W0+W1), 512 blocks/batch x 2048 els.
// z=1: Qb = bf16(Q),      512 blocks/batch x 4096 els.
__global__ __launch_bounds__(256) void qcvt_wsum(
    const float* __restrict__ Q, const u16_t* __restrict__ W0,
    const u16_t* __restrict__ W1, u16_t* __restrict__ Qb,
    u16_t* __restrict__ Wb, size_t nQbatch, size_t nWbatch) {
  const int batch = blockIdx.y;
  if (blockIdx.z == 0) {
    const size_t base = (size_t)batch * nWbatch +
                        (size_t)blockIdx.x * 2048 + threadIdx.x * 8;
    const uint4 u0 = *(const uint4*)(W0 + base);
    const uint4 u1 = *(const uint4*)(W1 + base);
    const u16_t* p0 = (const u16_t*)&u0;
    const u16_t* p1 = (const u16_t*)&u1;
    u16_t o[8];
#pragma unroll
    for (int j = 0; j < 8; ++j) o[j] = f2b(b2f(p0[j]) + b2f(p1[j]));
    *(uint4*)(Wb + base) = *(const uint4*)o;
  } else {
    const size_t base = (size_t)batch * nQbatch +
                        (size_t)blockIdx.x * 4096 + threadIdx.x * 16;
    const float* src = Q + base;
    u16_t* dst = Qb + base;
#pragma unroll
    for (int half = 0; half < 2; ++half) {
      const float4 a = *(const float4*)(src + half * 8);
      const float4 b = *(const float4*)(src + half * 8 + 4);
      unsigned o[4] = {pack2(a.x, a.y), pack2(a.z, a.w),
                       pack2(b.x, b.y), pack2(b.z, b.w)};
      *(uint4*)(dst + half * 8) = *(const uint4*)o;
    }
  }
}

// ---------------------------------------------------------------------------
extern "C" void kernel_launch(void* const* d_in, const int* in_sizes, int n_in,
                              void* d_out, int out_size, void* d_ws, size_t ws_size,
                              hipStream_t stream) {
  const int B = 8, M = 2048, L = 2048, H = 1024;
  const int ldT = L + 16;  // padded Kt/Vt row stride

  const float* q = (const float*)d_in[0];  // [B,M,H] fp32
  const float* k = (const float*)d_in[1];  // [B,L,H] fp32
  const float* v = (const float*)d_in[2];  // [B,L,H] fp32

  const size_t nKtP = (size_t)B * H * ldT;  // padded els
  const size_t nW   = (size_t)B * H * H;
  const size_t need = (2 * nKtP + 2 * nW) * sizeof(u16_t);  // ~101 MB
  if (ws_size < need) return;

  u16_t* Kt = (u16_t*)d_ws;   // [B,H,ldT]; reused as Qb [B,M,H] after gemm1
  u16_t* Vt = Kt + nKtP;      // [B,H,ldT]; reused as Wb [B,H,H] after gemm1
  u16_t* W0 = Vt + nKtP;      // [B,H,H] half-L partial 0
  u16_t* W1 = W0 + nW;        // [B,H,H] half-L partial 1
  u16_t* Qb = Kt;
  u16_t* Wb = Vt;

  // 1. K,V transpose+convert into padded [B,H,ldT].
  transpose_kv<<<dim3(H / 64, L / 512, 16), dim3(256), 0, stream>>>(
      k, v, Kt, Vt, L, H, ldT);

  // 2. GEMM1 split-L x2: W{0,1}[j][h] = sum_{half} Vt[j][l]*Kt[h][l]
  //    256 blocks (16 tiles x 2 kh x 8 batches), 512 threads.
  gemm1_kv<<<dim3(B * 16 * 2), dim3(512), 0, stream>>>(
      Vt, Kt, W0, H, L / 2, ldT, (long)H * ldT, (long)H * ldT, (long)H * H,
      (long)B * H * H);

  // 3. Wb = bf16(W0+W1); Qb = bf16(Q).
  qcvt_wsum<<<dim3(512, B, 2), dim3(256), 0, stream>>>(
      q, W0, W1, Qb, Wb, (size_t)M * H, (size_t)H * H);

  // 4. GEMM2: O[m][j] = sum_h Qb[m][h]*Wb[j][h]
  //    256 blocks (32 tiles x 8 batches), 512 threads.
  gemm2_qw<<<dim3(B * 32), dim3(512), 0, stream>>>(
      Qb, Wb, (float*)d_out, H, H, (long)M * H, (long)H * H, (long)M * H);
}

// Round 5
// 300.945 us; speedup vs baseline: 1.0986x; 1.0265x over previous
//
#include <hip/hip_runtime.h>
#include <hip/hip_bf16.h>

// SeqAttention: out = (Q K^T) V  ==  Q (K^T V)   [softmax + key_pe are dead code]
// B=8, M=2048, L=2048, H=1024. fp32 in/out; bf16 MFMA internal.
//
// R9 structure (4 launches) — resubmit after infra failure:
//   1. transpose_kv: K,V fp32 [B,L,H] -> bf16 PANELS Kt,Vt [B][p][h][32], p=l/32.
//      One block per panel: reads 32 FULL 4KB rows (128KB contiguous), writes one
//      64KB contiguous blob. No strided DRAM traffic on either side.
//   2. gemm1_kv:  split-L x2: W{0,1}[b][j][h] = sum_{l in half} Vt[j][l]*Kt[h][l]
//      256^2 x BK64, 512 thr, double-buffered LDS, PANEL staging (contiguous).
//   3. qcvt_wsum: z=0: Wb = bf16(W0+W1); z=1: Qb = bf16(Q)
//   4. gemm2_qw:  O[b][m][j] = sum_h Qb[m][h]*Wb[j][h] (fp32 out), linear staging.

typedef __bf16 bf16x8 __attribute__((ext_vector_type(8)));
typedef float f32x4 __attribute__((ext_vector_type(4)));
typedef unsigned short u16_t;

#define GLD_LDS16(g, l)                                                        \
  __builtin_amdgcn_global_load_lds(                                            \
      (const __attribute__((address_space(1))) void*)(g),                      \
      (__attribute__((address_space(3))) void*)(l), 16, 0, 0)

static __device__ inline u16_t f2b(float x) {
  __hip_bfloat16 h = __float2bfloat16(x);
  u16_t u;
  __builtin_memcpy(&u, &h, 2);
  return u;
}
static __device__ inline unsigned pack2(float a, float b) {
  return (unsigned)f2b(a) | ((unsigned)f2b(b) << 16);
}
static __device__ inline float b2f(u16_t u) {
  unsigned v = (unsigned)u << 16;
  float f;
  __builtin_memcpy(&f, &v, 4);
  return f;
}

// ---------------------------------------------------------------------------
// Panel transpose. Panel p covers l in [32p, 32p+32); blob layout [h][32] u16,
// blob stride 32768 els. z<8: K-batch z; z>=8: V-batch z-8.
// Read: row 2u,2u+1 fully contiguous (each wave-instr = 4KB). LDS u32 pair-tile
// [1024 h][17] with XOR-swizzled column (key s(t) = (t + (t>>4)) & 15, t = h>>2).
// Write: 4 threads per h-row, 16B each -> 64B/row, 4KB contiguous per wave-instr.
__global__ __launch_bounds__(256) void transpose_kv(
    const float* __restrict__ Kin, const float* __restrict__ Vin,
    u16_t* __restrict__ Kt, u16_t* __restrict__ Vt, int L, int Hd) {
  __shared__ unsigned tile[1024 * 17];  // 69632 B
  const int bz = blockIdx.z;
  const float* in = (bz < 8) ? Kin : Vin;
  u16_t* out = (bz < 8) ? Kt : Vt;
  const int batch = bz & 7;
  const int p = blockIdx.x;  // 0..63
  in  += (size_t)batch * L * Hd + (size_t)p * 32 * Hd;
  out += (size_t)batch * L * Hd + (size_t)p * 32 * Hd;  // panel blob (32*Hd els)

  const int tid = threadIdx.x;
  const int swz = (tid + (tid >> 4)) & 15;  // write-side key; t = h>>2 = tid

  // Read phase: 16 l-pairs; group 4 pairs (8 float4 loads) before packing.
#pragma unroll
  for (int g = 0; g < 4; ++g) {
    float4 a[4], b[4];
#pragma unroll
    for (int uu = 0; uu < 4; ++uu) {
      const int u = g * 4 + uu;
      a[uu] = *(const float4*)(in + (size_t)(2 * u) * Hd + tid * 4);
      b[uu] = *(const float4*)(in + (size_t)(2 * u + 1) * Hd + tid * 4);
    }
#pragma unroll
    for (int uu = 0; uu < 4; ++uu) {
      const int u = g * 4 + uu;
      const int col = u ^ swz;
      tile[(4 * tid + 0) * 17 + col] = pack2(a[uu].x, b[uu].x);
      tile[(4 * tid + 1) * 17 + col] = pack2(a[uu].y, b[uu].y);
      tile[(4 * tid + 2) * 17 + col] = pack2(a[uu].z, b[uu].z);
      tile[(4 * tid + 3) * 17 + col] = pack2(a[uu].w, b[uu].w);
    }
  }
  __syncthreads();

  // Write phase: h = 64g + (tid>>2); chunk c = tid&3 (dwords 4c..4c+3).
  const int c = tid & 3;
  const int hr = tid >> 2;
#pragma unroll
  for (int g = 0; g < 16; ++g) {
    const int h = g * 64 + hr;
    const int t = h >> 2;
    const int s = (t + (t >> 4)) & 15;
    unsigned dw[4];
#pragma unroll
    for (int j = 0; j < 4; ++j) dw[j] = tile[h * 17 + ((4 * c + j) ^ s)];
    *(uint4*)(out + (size_t)h * 32 + c * 8) = *(const uint4*)dw;
  }
}

// ---------------------------------------------------------------------------
static __device__ inline void store_c(float* p, float v) { *p = v; }
static __device__ inline void store_c(u16_t* p, float v) { *p = f2b(v); }

// 256^2 x BK64 GEMM body, 512 threads (8 waves = 2m x 4n), per-wave 128x64.
// C[m][n] = sum_{k in split kh} A[m][k]*Bt[n][k].
// PANEL=true: A/Bt are packed panels [p][row=0..1023][32] (p = k/32, panel
//   stride 32768 els); element (row,k) at (k>>5)*32768 + row*32 + (k&31).
//   K-step advance (k0 % 32 == 0): + k0*1024.
// PANEL=false: row-major, row stride = K (gemm2: Qb/Wb contiguous rows).
// blockIdx.x = ((kh*Tiles + t) << 3) | batch;  Tiles = 1<<tile_shift;
// t -> (tm = t>>2, tn = t&3); N must be 1024. LDS swizzle: slot = chunk^(row&7).
template <typename OutT, bool PANEL>
static __device__ inline void gemm256_body(
    const u16_t* __restrict__ A, const u16_t* __restrict__ Bt,
    OutT* __restrict__ C, int N, int K,
    long sA, long sB, long sC, int tile_shift, long sCsplit) {
  __shared__ __align__(16) u16_t As[2][256 * 64];
  __shared__ __align__(16) u16_t Bs[2][256 * 64];

  const int batch = blockIdx.x & 7;
  const unsigned u = blockIdx.x >> 3;
  const int kh = (int)(u >> tile_shift);
  const unsigned t = u & ((1u << tile_shift) - 1u);
  const int m0 = (int)(t >> 2) * 256;
  const int n0 = (int)(t & 3) * 256;

  A  += (size_t)batch * (size_t)sA +
        (PANEL ? (size_t)kh * (size_t)K * 1024 : (size_t)kh * (size_t)K);
  Bt += (size_t)batch * (size_t)sB +
        (PANEL ? (size_t)kh * (size_t)K * 1024 : (size_t)kh * (size_t)K);
  C  += (size_t)batch * (size_t)sC + (size_t)kh * (size_t)sCsplit;

  const int tid = threadIdx.x;
  const int lane = tid & 63;
  const int w  = tid >> 6;  // 0..7
  const int wm = w & 1;
  const int wn = w >> 1;    // 0..3
  const int s  = lane & 15;
  const int q  = lane >> 4;
  const int s7 = s & 7;

  // Staging addresses: i = tid + 512*j covers 2048 slots (256 rows x 8 chunks).
  const u16_t* gA[4];
  const u16_t* gB[4];
  int lofs[4];
#pragma unroll
  for (int j = 0; j < 4; ++j) {
    const int i = tid + 512 * j;
    const int row = i >> 3;                    // 0..255
    const int gchunk = (i & 7) ^ (row & 7);    // pre-swizzled global source
    if constexpr (PANEL) {
      gA[j] = A  + (size_t)(gchunk >> 2) * 32768 + (size_t)(m0 + row) * 32 +
              (gchunk & 3) * 8;
      gB[j] = Bt + (size_t)(gchunk >> 2) * 32768 + (size_t)(n0 + row) * 32 +
              (gchunk & 3) * 8;
    } else {
      gA[j] = A  + (size_t)(m0 + row) * K + gchunk * 8;
      gB[j] = Bt + (size_t)(n0 + row) * K + gchunk * 8;
    }
    lofs[j] = i * 8;                           // linear LDS dest
  }

  f32x4 acc[8][4];
#pragma unroll
  for (int r = 0; r < 8; ++r)
#pragma unroll
    for (int c = 0; c < 4; ++c) acc[r][c] = (f32x4){0.f, 0.f, 0.f, 0.f};

  auto STAGE = [&](u16_t* dA, u16_t* dB, int k0) {
    const size_t ko = PANEL ? (size_t)k0 * 1024 : (size_t)k0;
#pragma unroll
    for (int j = 0; j < 4; ++j) GLD_LDS16(gA[j] + ko, dA + lofs[j]);
#pragma unroll
    for (int j = 0; j < 4; ++j) GLD_LDS16(gB[j] + ko, dB + lofs[j]);
  };

  auto COMPUTE = [&](const u16_t* As_, const u16_t* Bs_) {
#pragma unroll
    for (int kk = 0; kk < 2; ++kk) {
      const int slot = (kk * 4 + q) ^ s7;
      bf16x8 bfr[4];
#pragma unroll
      for (int c = 0; c < 4; ++c)
        bfr[c] = *(const bf16x8*)(Bs_ + (64 * wn + 16 * c + s) * 64 + slot * 8);
#pragma unroll
      for (int r = 0; r < 8; ++r) {
        const bf16x8 af =
            *(const bf16x8*)(As_ + (128 * wm + 16 * r + s) * 64 + slot * 8);
#pragma unroll
        for (int c = 0; c < 4; ++c)
          acc[r][c] = __builtin_amdgcn_mfma_f32_16x16x32_bf16(af, bfr[c],
                                                              acc[r][c], 0, 0, 0);
      }
    }
  };

  const int nt = K / 64;  // 16 for both gemms (even)
  STAGE(As[0], Bs[0], 0);
  __syncthreads();
  for (int tt = 0; tt < nt; tt += 2) {
    if (tt + 1 < nt) STAGE(As[1], Bs[1], (tt + 1) * 64);  // flies under MFMA
    COMPUTE(As[0], Bs[0]);
    __syncthreads();
    if (tt + 2 < nt) STAGE(As[0], Bs[0], (tt + 2) * 64);
    COMPUTE(As[1], Bs[1]);
    __syncthreads();
  }

  // C/D layout (m89-verified): col = lane&15, row = (lane>>4)*4 + reg
#pragma unroll
  for (int r = 0; r < 8; ++r) {
#pragma unroll
    for (int c = 0; c < 4; ++c) {
      const int col = n0 + 64 * wn + 16 * c + s;
#pragma unroll
      for (int e = 0; e < 4; ++e) {
        const int row = m0 + 128 * wm + 16 * r + q * 4 + e;
        store_c(&C[(size_t)row * N + col], acc[r][c][e]);
      }
    }
  }
}

// GEMM1: W-halves from panel Vt,Kt. grid.x = B * 16 * 2 (tile_shift=4).
__global__ __launch_bounds__(512) void gemm1_kv(
    const u16_t* __restrict__ Vt, const u16_t* __restrict__ Kt,
    u16_t* __restrict__ W0, int N, int K, long sA, long sB, long sC,
    long sCsplit) {
  gemm256_body<u16_t, true>(Vt, Kt, W0, N, K, sA, sB, sC, 4, sCsplit);
}

// GEMM2: O from Qb,Wb (row-major). grid.x = B * 32 (tile_shift=5, kh=0).
__global__ __launch_bounds__(512) void gemm2_qw(
    const u16_t* __restrict__ Qb, const u16_t* __restrict__ Wb,
    float* __restrict__ C, int N, int K, long sA, long sB, long sC) {
  gemm256_body<float, false>(Qb, Wb, C, N, K, sA, sB, sC, 5, 0);
}

// ---------------------------------------------------------------------------
// z=0: Wb = bf16(W0+W1), 512 blocks/batch x 2048 els.
// z=1: Qb = bf16(Q),      512 blocks/batch x 4096 els.
__global__ __launch_bounds__(256) void qcvt_wsum(
    const float* __restrict__ Q, const u16_t* __restrict__ W0,
    const u16_t* __restrict__ W1, u16_t* __restrict__ Qb,
    u16_t* __restrict__ Wb, size_t nQbatch, size_t nWbatch) {
  const int batch = blockIdx.y;
  if (blockIdx.z == 0) {
    const size_t base = (size_t)batch * nWbatch +
                        (size_t)blockIdx.x * 2048 + threadIdx.x * 8;
    const uint4 u0 = *(const uint4*)(W0 + base);
    const uint4 u1 = *(const uint4*)(W1 + base);
    const u16_t* p0 = (const u16_t*)&u0;
    const u16_t* p1 = (const u16_t*)&u1;
    u16_t o[8];
#pragma unroll
    for (int j = 0; j < 8; ++j) o[j] = f2b(b2f(p0[j]) + b2f(p1[j]));
    *(uint4*)(Wb + base) = *(const uint4*)o;
  } else {
    const size_t base = (size_t)batch * nQbatch +
                        (size_t)blockIdx.x * 4096 + threadIdx.x * 16;
    const float* src = Q + base;
    u16_t* dst = Qb + base;
#pragma unroll
    for (int half = 0; half < 2; ++half) {
      const float4 a = *(const float4*)(src + half * 8);
      const float4 b = *(const float4*)(src + half * 8 + 4);
      unsigned o[4] = {pack2(a.x, a.y), pack2(a.z, a.w),
                       pack2(b.x, b.y), pack2(b.z, b.w)};
      *(uint4*)(dst + half * 8) = *(const uint4*)o;
    }
  }
}

// ---------------------------------------------------------------------------
extern "C" void kernel_launch(void* const* d_in, const int* in_sizes, int n_in,
                              void* d_out, int out_size, void* d_ws, size_t ws_size,
                              hipStream_t stream) {
  const int B = 8, M = 2048, L = 2048, H = 1024;

  const float* q = (const float*)d_in[0];  // [B,M,H] fp32
  const float* k = (const float*)d_in[1];  // [B,L,H] fp32
  const float* v = (const float*)d_in[2];  // [B,L,H] fp32

  const size_t nKt = (size_t)B * H * L;  // 16.78M els
  const size_t nW  = (size_t)B * H * H;  // 8.39M els
  const size_t need = (2 * nKt + 2 * nW) * sizeof(u16_t);  // 100.7 MB
  if (ws_size < need) return;

  u16_t* Kt = (u16_t*)d_ws;  // [B][64 panels][1024][32]; reused as Qb after gemm1
  u16_t* Vt = Kt + nKt;      // same layout; reused as Wb after gemm1
  u16_t* W0 = Vt + nKt;      // [B,H,H] half-L partial 0
  u16_t* W1 = W0 + nW;       // [B,H,H] half-L partial 1
  u16_t* Qb = Kt;
  u16_t* Wb = Vt;

  // 1. K,V transpose+convert into packed panels.
  transpose_kv<<<dim3(L / 32, 1, 16), dim3(256), 0, stream>>>(k, v, Kt, Vt, L, H);

  // 2. GEMM1 split-L x2: W{0,1}[j][h] = sum_{half} Vt[j][l]*Kt[h][l]
  gemm1_kv<<<dim3(B * 16 * 2), dim3(512), 0, stream>>>(
      Vt, Kt, W0, H, L / 2, (long)H * L, (long)H * L, (long)H * H,
      (long)B * H * H);

  // 3. Wb = bf16(W0+W1); Qb = bf16(Q).
  qcvt_wsum<<<dim3(512, B, 2), dim3(256), 0, stream>>>(
      q, W0, W1, Qb, Wb, (size_t)M * H, (size_t)H * H);

  // 4. GEMM2: O[m][j] = sum_h Qb[m][h]*Wb[j][h]
  gemm2_qw<<<dim3(B * 32), dim3(512), 0, stream>>>(
      Qb, Wb, (float*)d_out, H, H, (long)M * H, (long)H * H, (long)M * H);
}